// Round 5
// baseline (662.067 us; speedup 1.0000x reference)
//
#include <hip/hip_runtime.h>
#include <math.h>

// alpha-entmax via bisection (ref: entmax.EntmaxBisect, 50 iters).
// Register-resident row version.
//
// Facts exploited:
//  * Every bisection iterate tau >= gmax-1, so elements with X <= gmax-1
//    contribute 0 to all sums and output exactly 0 (~98% of row here).
//  * alpha=1.5: f(tau)=sum max(X-tau,0)^2-1 convex decreasing; Newton from
//    tau_lo converges monotonically (tangent below convex fn), early exit.
// Structure: 1 block/row, 512 thr, 64 f32/thread row cache in VGPRs.
//  load all 16 float4/thread (16KB/wave in flight, pure read stream)
//  -> exact block max (shfl + LDS, no atomics in stream)
//  -> filter from regs with exact threshold, append ~500 cand (1 atomic/thr)
//  -> wave-0 Newton on candidates
//  -> epilogue: store ALL elements from regs (no zero-fill, no scatter).
// R1 tried this with __launch_bounds__(512,8) -> 64 VGPR cap -> scratch
// spills (WRITE 448MB). (512,4) gives 128 VGPRs; X[64]+overhead fits.
// R3/R4 post-mortem: streamed filter w/ LDS round-trips plateaued at
// 2.5 TB/s, VALU 18% -- latency-chain bound; this removes all LDS/atomic
// traffic from the load loop and all store traffic except the final clean
// 262MB write stream.

#define D_DIM   32000
#define NV4     (D_DIM / 4)          // 8000 float4 per row
#define BLOCK   512
#define NWAVE   (BLOCK / 64)         // 8
#define KITER   16                   // ceil(8000/512); last chunk partial
#define VPT     (4 * KITER)          // 64 floats per thread
#define CAP     6144                 // candidate capacity (val+u16 idx = 36 KB)
#define NEWTON_MAX 30
#define NITER   50

__device__ __forceinline__ float wave_sum(float v) {
#pragma unroll
    for (int off = 32; off > 0; off >>= 1) v += __shfl_xor(v, off, 64);
    return v;
}
__device__ __forceinline__ float wave_max(float v) {
#pragma unroll
    for (int off = 32; off > 0; off >>= 1) v = fmaxf(v, __shfl_xor(v, off, 64));
    return v;
}
__device__ __forceinline__ float pf(float z, bool sq, float expo) {
    z = fmaxf(z, 0.0f);
    return sq ? z * z : powf(z, expo);
}

__global__ __launch_bounds__(BLOCK, 4)   // 128 VGPR budget: X[64] fits, no spill
void entmax_bisect_kernel(const float* __restrict__ x,
                          const float* __restrict__ alpha_p,
                          float* __restrict__ out) {
    const int row  = blockIdx.x;
    const int tid  = threadIdx.x;
    const int lane = tid & 63;
    const int wid  = tid >> 6;

    __shared__ float          s_val[CAP];    // 24 KB
    __shared__ unsigned short s_idx[CAP];    // 12 KB
    __shared__ float          s_red[NWAVE];
    __shared__ float          s_bc[2];       // tau_final, sum_p
    __shared__ int            s_cnt;

    const float alpha = alpha_p[0];
    const float am1   = alpha - 1.0f;
    const float expo  = 1.0f / am1;
    const bool  sq    = (expo == 2.0f);      // alpha == 1.5 exact fast path

    const float4* __restrict__ x4 = (const float4*)(x + (size_t)row * D_DIM);
    float4*       __restrict__ o4 = (float4*)(out + (size_t)row * D_DIM);

    if (tid == 0) s_cnt = 0;

    // ---- Phase 1: load entire row slice into registers (16 KB/wave in flight)
    float X[VPT];
#pragma unroll
    for (int k = 0; k < KITER; ++k) {
        const int i4 = tid + k * BLOCK;
        if (i4 < NV4) {
            const float4 v = x4[i4];
            X[4 * k + 0] = v.x * am1;
            X[4 * k + 1] = v.y * am1;
            X[4 * k + 2] = v.z * am1;
            X[4 * k + 3] = v.w * am1;
        } else {
            X[4 * k + 0] = -INFINITY; X[4 * k + 1] = -INFINITY;
            X[4 * k + 2] = -INFINITY; X[4 * k + 3] = -INFINITY;
        }
    }

    // ---- Phase 2: exact block max (registers -> shfl -> LDS -> broadcast)
    float mx = X[0];
#pragma unroll
    for (int j = 1; j < VPT; ++j) mx = fmaxf(mx, X[j]);
    mx = wave_max(mx);
    if (lane == 0) s_red[wid] = mx;
    __syncthreads();
    float max_val = s_red[0];
#pragma unroll
    for (int w = 1; w < NWAVE; ++w) max_val = fmaxf(max_val, s_red[w]);
    const float tau_lo0 = max_val - 1.0f;

    // ---- Phase 3: filter from registers, append candidates (1 atomic/thread)
    {
        int cnt = 0;
#pragma unroll
        for (int j = 0; j < VPT; ++j) cnt += (int)(X[j] > tau_lo0);
        if (cnt) {
            int base = atomicAdd(&s_cnt, cnt);
#pragma unroll
            for (int k = 0; k < KITER; ++k) {
#pragma unroll
                for (int c = 0; c < 4; ++c) {
                    const float xv = X[4 * k + c];
                    if (xv > tau_lo0) {
                        if (base < CAP) {
                            s_val[base] = xv;
                            s_idx[base] = (unsigned short)((tid + k * BLOCK) * 4 + c);
                        }
                        ++base;
                    }
                }
            }
        }
    }
    __syncthreads();
    const int n_act = s_cnt;

    if (n_act <= CAP) {
        // ---- Phase 4: solve on wave 0
        if (wid == 0) {
            float tau, S;
            if (sq) {
                tau = tau_lo0;                      // monotone Newton
                for (int it = 0; it < NEWTON_MAX; ++it) {
                    float s1 = 0.f, s2 = 0.f;
                    for (int i = lane; i < n_act; i += 64) {
                        const float z = fmaxf(s_val[i] - tau, 0.f);
                        s1 += z; s2 += z * z;
                    }
#pragma unroll
                    for (int off = 32; off > 0; off >>= 1) {
                        s1 += __shfl_xor(s1, off, 64);
                        s2 += __shfl_xor(s2, off, 64);
                    }
                    const float dtau = (s2 - 1.0f) / fmaxf(2.0f * s1, 1e-30f);
                    tau += dtau;
                    if (dtau < 1e-7f * fmaxf(1.0f, fabsf(tau))) break;
                }
                float s2 = 0.f;
                for (int i = lane; i < n_act; i += 64) {
                    const float z = fmaxf(s_val[i] - tau, 0.f);
                    s2 += z * z;
                }
                S = wave_sum(s2);
            } else {
                // generic alpha: faithful 50-step bisection over candidates
                const float tau_hi = max_val - powf(1.0f / (float)D_DIM, am1);
                float dm = tau_hi - tau_lo0;
                float s = 0.f;
                for (int i = lane; i < n_act; i += 64)
                    s += pf(s_val[i] - tau_lo0, sq, expo);
                s = wave_sum(s);
                const float f_lo = s - 1.0f;
                float tlo = tau_lo0, tau_m = tau_lo0, fsum = s;
                for (int it = 0; it < NITER; ++it) {
                    dm *= 0.5f;
                    tau_m = tlo + dm;
                    float t = 0.f;
                    for (int i = lane; i < n_act; i += 64)
                        t += pf(s_val[i] - tau_m, sq, expo);
                    t = wave_sum(t);
                    fsum = t;
                    if ((t - 1.0f) * f_lo >= 0.0f) tlo = tau_m;
                }
                tau = tau_m; S = fsum;
            }
            if (lane == 0) { s_bc[0] = tau; s_bc[1] = S; }
        }
        __syncthreads();

        // ---- Phase 5: epilogue — store EVERYTHING from registers
        const float tau_f = s_bc[0];
        const float invS  = 1.0f / s_bc[1];
#pragma unroll
        for (int k = 0; k < KITER; ++k) {
            const int i4 = tid + k * BLOCK;
            if (i4 < NV4) {
                float4 o;
                o.x = pf(X[4 * k + 0] - tau_f, sq, expo) * invS;
                o.y = pf(X[4 * k + 1] - tau_f, sq, expo) * invS;
                o.z = pf(X[4 * k + 2] - tau_f, sq, expo) * invS;
                o.w = pf(X[4 * k + 3] - tau_f, sq, expo) * invS;
                o4[i4] = o;
            }
        }
    } else {
        // ---- Overflow fallback (pathological inputs): full-block 50-step
        //      bisection over register-resident X. (-INF pads give pf()=0.)
        const float tau_hi = max_val - powf(1.0f / (float)D_DIM, am1);
        float dm = tau_hi - tau_lo0;
        float s = 0.f;
#pragma unroll
        for (int j = 0; j < VPT; ++j) s += pf(X[j] - tau_lo0, sq, expo);
        s = wave_sum(s);
        if (lane == 0) s_red[wid] = s;
        __syncthreads();
        float tot = 0.f;
#pragma unroll
        for (int w = 0; w < NWAVE; ++w) tot += s_red[w];
        const float f_lo = tot - 1.0f;
        float tlo = tau_lo0, tau_m = tau_lo0, fsum = tot;
        for (int it = 0; it < NITER; ++it) {
            dm *= 0.5f;
            tau_m = tlo + dm;
            float t = 0.f;
#pragma unroll
            for (int j = 0; j < VPT; ++j) t += pf(X[j] - tau_m, sq, expo);
            t = wave_sum(t);
            __syncthreads();                // protect s_red reuse
            if (lane == 0) s_red[wid] = t;
            __syncthreads();
            float tt = 0.f;
#pragma unroll
            for (int w = 0; w < NWAVE; ++w) tt += s_red[w];
            fsum = tt;
            if ((tt - 1.0f) * f_lo >= 0.0f) tlo = tau_m;
        }
        const float invS = 1.0f / fsum;
#pragma unroll
        for (int k = 0; k < KITER; ++k) {
            const int i4 = tid + k * BLOCK;
            if (i4 < NV4) {
                float4 o;
                o.x = pf(X[4 * k + 0] - tau_m, sq, expo) * invS;
                o.y = pf(X[4 * k + 1] - tau_m, sq, expo) * invS;
                o.z = pf(X[4 * k + 2] - tau_m, sq, expo) * invS;
                o.w = pf(X[4 * k + 3] - tau_m, sq, expo) * invS;
                o4[i4] = o;
            }
        }
    }
}

extern "C" void kernel_launch(void* const* d_in, const int* in_sizes, int n_in,
                              void* d_out, int out_size, void* d_ws, size_t ws_size,
                              hipStream_t stream) {
    const float* x       = (const float*)d_in[0];
    const float* alpha_p = (const float*)d_in[1];
    float* out           = (float*)d_out;
    const int rows       = in_sizes[0] / D_DIM;   // 2048
    entmax_bisect_kernel<<<rows, BLOCK, 0, stream>>>(x, alpha_p, out);
}